// Round 7
// baseline (381.871 us; speedup 1.0000x reference)
//
#include <hip/hip_runtime.h>

// Collapse: out = ((P3@M.T + 16c)@M.T + 4c)@M.T + c,  M = Wzf@Wsum.
// Materialize B1 = M.T (row-major B1[h][j] = M[j][h]) = Wsum.T @ Wzf.T,
// then B2 = B1@B1, u = 4c@B1 + c, Y1 = P3·B1 + 16c, out = Y1·B2 + u.
// Broadcast-GEMM: lanes = output rows, A staged in LDS ([row][k], pad 129),
// B[k][j] read as wave-uniform scalar loads (SGPR operand of v_fmac) ->
// ~0.25 LDS-bytes/FMA, FMA-bound (~7 us per 512-deep GEMM).
// Dispatches: D1{pool,WzfT,c0}(2240) -> D2{B1}(64) -> D3{Y1,B2,u}(194) -> D4{out}(128)

#define HD 512

// ================= broadcast GEMM =================
// C[i0+lane, j0w + 0..15] over K=512, k-tiles of 128.
// AMODE 0: As[r][k] = A[(i0+r)*512 + k0+k]  (direct row-major)
// AMODE 1: As[r][k] = sum_q Wz[q][(k0+k)*512 + (i0+r)]  (Wsum transpose-sum)
struct GemmSmem { float As[64][129]; };   // 33024 B

template<int AMODE>
__device__ __forceinline__
void bgemm(const float* __restrict__ A, const float* __restrict__ B,
           float* __restrict__ C, const float* __restrict__ bias,
           float bscale, int i0, int j0, GemmSmem& sm) {
    const int t = threadIdx.x, lane = t & 63, w = t >> 6;
    const int j0w = __builtin_amdgcn_readfirstlane(j0 + w * 16);

    float acc[16] = {};

    for (int k0 = 0; k0 < HD; k0 += 128) {
        __syncthreads();
        if (AMODE == 0) {
            // thread t: row = t>>5 (+8 per pass), k4 = (t&31)*4
            const int r = t >> 5, k4 = (t & 31) << 2;
            #pragma unroll
            for (int p = 0; p < 8; ++p) {
                float4 v = *(const float4*)&A[(size_t)(i0 + r + 8 * p) * HD + k0 + k4];
                *(float4*)&sm.As[r + 8 * p][k4] = v;
            }
        } else {
            // thread t: h4 = (t&15)*4, m = t>>4 (+16 per pass)
            const int h4 = (t & 15) << 2, m = t >> 4;
            #pragma unroll
            for (int p = 0; p < 8; ++p) {
                const float* wp = &A[(size_t)(k0 + m + 16 * p) * HD + i0 + h4];
                float4 s = *(const float4*)wp;
                #pragma unroll
                for (int q = 1; q < 4; ++q) {
                    float4 v = *(const float4*)(wp + q * 262144);
                    s.x += v.x; s.y += v.y; s.z += v.z; s.w += v.w;
                }
                sm.As[h4 + 0][m + 16 * p] = s.x;
                sm.As[h4 + 1][m + 16 * p] = s.y;
                sm.As[h4 + 2][m + 16 * p] = s.z;
                sm.As[h4 + 3][m + 16 * p] = s.w;
            }
        }
        __syncthreads();

        const float* bbase = B + ((size_t)k0 << 9) + j0w;
        #pragma unroll 4
        for (int k = 0; k < 128; k += 4) {
            float4 a = *(const float4*)&sm.As[lane][k];   // 4 ks for this row
            float av[4] = {a.x, a.y, a.z, a.w};
            #pragma unroll
            for (int dk = 0; dk < 4; ++dk) {
                const float* br = bbase + ((size_t)(k + dk) << 9); // uniform -> s_load
                #pragma unroll
                for (int n = 0; n < 16; ++n)
                    acc[n] = fmaf(av[dk], br[n], acc[n]);
            }
        }
    }

    #pragma unroll
    for (int n = 0; n < 16; ++n)
        if (bias) acc[n] += bscale * bias[j0w + n];        // uniform adds
    float* cp = &C[(size_t)(i0 + lane) * HD + j0w];
    #pragma unroll
    for (int n = 0; n < 4; ++n)
        *(float4*)(cp + 4 * n) = make_float4(acc[4*n], acc[4*n+1], acc[4*n+2], acc[4*n+3]);
}

// ================= D1: pool + WzfT + c0 =================
struct D1Smem { union { float tp[64][65]; float4 red[192]; } u; };

__global__ __launch_bounds__(256) void kD1(
        const float* __restrict__ x, const float* __restrict__ Wz,
        const float* __restrict__ bz, const float* __restrict__ Wzf,
        const float* __restrict__ bzf,
        float* __restrict__ P3, float* __restrict__ WzfT, float* __restrict__ c0) {
    __shared__ D1Smem sm;
    const int b = blockIdx.x, t = threadIdx.x, lane = t & 63, w = t >> 6;
    if (b < 2048) {
        // pool: block = (tree, col-half). 64 rows x 64 col4s. thread: col4 =
        // cbase+lane, rows w+4i (16 loads, 2 batches of 8 in flight).
        const int tree = b >> 1, cbase = (b & 1) << 6;
        const float4* xp = (const float4*)x + (size_t)tree * 8192 + w * 128 + cbase + lane;
        float4 acc = make_float4(0.f, 0.f, 0.f, 0.f);
        {
            float4 v[8];
            #pragma unroll
            for (int i = 0; i < 8; ++i) v[i] = xp[(size_t)i * 512];
            #pragma unroll
            for (int i = 0; i < 8; ++i) {
                acc.x += v[i].x; acc.y += v[i].y; acc.z += v[i].z; acc.w += v[i].w;
            }
            #pragma unroll
            for (int i = 0; i < 8; ++i) v[i] = xp[(size_t)(i + 8) * 512];
            #pragma unroll
            for (int i = 0; i < 8; ++i) {
                acc.x += v[i].x; acc.y += v[i].y; acc.z += v[i].z; acc.w += v[i].w;
            }
        }
        if (w > 0) sm.u.red[(w - 1) * 64 + lane] = acc;
        __syncthreads();
        if (w == 0) {
            float4 r0 = sm.u.red[lane], r1 = sm.u.red[64 + lane], r2 = sm.u.red[128 + lane];
            acc.x += r0.x + r1.x + r2.x;
            acc.y += r0.y + r1.y + r2.y;
            acc.z += r0.z + r1.z + r2.z;
            acc.w += r0.w + r1.w + r2.w;
            ((float4*)P3)[tree * 128 + cbase + lane] = acc;
        }
    } else if (b < 2112) {
        // transpose 64x64 tile of Wzf
        const int bb = b - 2048;
        const int r0 = (bb >> 3) << 6, c0t = (bb & 7) << 6;
        const int rr = t >> 4, c4 = (t & 15) << 2;
        #pragma unroll
        for (int p = 0; p < 4; ++p) {
            float4 v = *(const float4*)&Wzf[(size_t)(r0 + rr + 16 * p) * HD + c0t + c4];
            sm.u.tp[c4 + 0][rr + 16 * p] = v.x;
            sm.u.tp[c4 + 1][rr + 16 * p] = v.y;
            sm.u.tp[c4 + 2][rr + 16 * p] = v.z;
            sm.u.tp[c4 + 3][rr + 16 * p] = v.w;
        }
        __syncthreads();
        #pragma unroll
        for (int p = 0; p < 4; ++p) {
            float4 o = make_float4(sm.u.tp[rr + 16 * p][c4 + 0],
                                   sm.u.tp[rr + 16 * p][c4 + 1],
                                   sm.u.tp[rr + 16 * p][c4 + 2],
                                   sm.u.tp[rr + 16 * p][c4 + 3]);
            *(float4*)&WzfT[(size_t)(c0t + rr + 16 * p) * HD + r0 + c4] = o;
        }
    } else {
        // c0[j] = 4*(dot(bsum, Wzf[j,:]) + bzf[j]); one output per wave
        const int j = (b - 2112) * 4 + w, hb = lane << 3;
        float4 s0 = *(const float4*)&bz[hb];
        float4 s1 = *(const float4*)&bz[hb + 4];
        #pragma unroll
        for (int q = 1; q < 4; ++q) {
            float4 t0 = *(const float4*)&bz[q * HD + hb];
            float4 t1 = *(const float4*)&bz[q * HD + hb + 4];
            s0.x += t0.x; s0.y += t0.y; s0.z += t0.z; s0.w += t0.w;
            s1.x += t1.x; s1.y += t1.y; s1.z += t1.z; s1.w += t1.w;
        }
        const float4* wr = (const float4*)&Wzf[(size_t)j * HD + hb];
        float4 w0 = wr[0], w1 = wr[1];
        float p = w0.x * s0.x + w0.y * s0.y + w0.z * s0.z + w0.w * s0.w
                + w1.x * s1.x + w1.y * s1.y + w1.z * s1.z + w1.w * s1.w;
        #pragma unroll
        for (int off = 32; off > 0; off >>= 1) p += __shfl_down(p, off);
        if (lane == 0) c0[j] = 4.f * (p + bzf[j]);
    }
}

// ================= D2: B1 = Wsum.T @ Wzf.T =================
__global__ __launch_bounds__(256) void kD2(
        const float* __restrict__ Wz, const float* __restrict__ WzfT,
        float* __restrict__ B1) {
    __shared__ GemmSmem sm;
    const int b = blockIdx.x;
    bgemm<1>(Wz, WzfT, B1, nullptr, 0.f, (b >> 3) << 6, (b & 7) << 6, sm);
}

// ================= D3: Y1, B2, u =================
__global__ __launch_bounds__(256) void kD3(
        const float* __restrict__ P3, const float* __restrict__ B1,
        const float* __restrict__ c0,
        float* __restrict__ Y1, float* __restrict__ B2, float* __restrict__ u) {
    __shared__ GemmSmem sm;
    const int b = blockIdx.x, t = threadIdx.x, lane = t & 63, w = t >> 6;
    if (b < 128) {
        bgemm<0>(P3, B1, Y1, c0, 16.f, (b >> 3) << 6, (b & 7) << 6, sm);
    } else if (b < 192) {
        const int bb = b - 128;
        bgemm<0>(B1, B1, B2, nullptr, 0.f, (bb >> 3) << 6, (bb & 7) << 6, sm);
    } else {
        // u[j] = 4*sum_h c0[h]*B1[h][j] + c0[j]; wave handles 64 js
        const int jb = ((b - 192) * 4 + w) << 6;
        float a = 0.f;
        for (int h = 0; h < HD; ++h)
            a = fmaf(c0[h], B1[(size_t)h * HD + jb + lane], a);  // c0[h] uniform
        u[jb + lane] = 4.f * a + c0[jb + lane];
    }
}

// ================= D4: out = Y1 @ B2 + u =================
__global__ __launch_bounds__(256) void kD4(
        const float* __restrict__ Y1, const float* __restrict__ B2,
        const float* __restrict__ u, float* __restrict__ out) {
    __shared__ GemmSmem sm;
    const int b = blockIdx.x;
    bgemm<0>(Y1, B2, out, u, 1.f, (b >> 3) << 6, (b & 7) << 6, sm);
}

extern "C" void kernel_launch(void* const* d_in, const int* in_sizes, int n_in,
                              void* d_out, int out_size, void* d_ws, size_t ws_size,
                              hipStream_t stream) {
    const float* x   = (const float*)d_in[0];
    const float* Wz  = (const float*)d_in[1];
    const float* bz  = (const float*)d_in[2];
    const float* Wzf = (const float*)d_in[3];
    const float* bzf = (const float*)d_in[4];
    float* out = (float*)d_out;

    float* ws   = (float*)d_ws;
    float* P3   = ws;                 // 1024*512
    float* Y1   = ws + 524288;        // 1024*512
    float* B1   = ws + 1048576;       // 512*512
    float* B2   = ws + 1310720;       // 512*512
    float* WzfT = ws + 1572864;       // 512*512
    float* c0   = ws + 1835008;       // 512
    float* u    = ws + 1835520;       // 512

    hipLaunchKernelGGL(kD1, dim3(2240), dim3(256), 0, stream,
                       x, Wz, bz, Wzf, bzf, P3, WzfT, c0);
    hipLaunchKernelGGL(kD2, dim3(64), dim3(256), 0, stream, Wz, WzfT, B1);
    hipLaunchKernelGGL(kD3, dim3(194), dim3(256), 0, stream,
                       P3, B1, c0, Y1, B2, u);
    hipLaunchKernelGGL(kD4, dim3(128), dim3(256), 0, stream, Y1, B2, u, out);
}

// Round 8
// 263.916 us; speedup vs baseline: 1.4469x; 1.4469x over previous
//
#include <hip/hip_runtime.h>

// Collapse: out = ((P3@M.T + 16c)@M.T + 4c)@M.T + c,  M = Wzf@Wsum.
// NT-form chain (Bt = operand with rows = B-cols):
//   WsumT = sum_q Wz[q].T ; M = NT(Wzf,WsumT) ; MT = NT(WsumT,Wzf)
//   M2 = NT(M,MT) = M@M ; Y1 = NT(P3,M)+16c ; u = 4c@M.T+c ; out = NT(Y1,M2)+u
// GEMMs use MFMA 16x16x32 bf16 with exact 2-term split (f = hi + lo, both
// bf16-truncated): A*B ~= Ah*Bh + Ah*Bl + Al*Bh  (rel err ~2e-5).
// D1{pool,WsumT,c0}(1216) -> D2{M,MT}(128) -> D3{Y1,M2,u}(320) -> D4{out}(128)

#define HD 512

typedef __attribute__((ext_vector_type(8))) short bf16x8;
typedef __attribute__((ext_vector_type(4))) float f32x4;

struct __align__(16) MfmaSmem {        // 20480 B
    unsigned short Ah[64][40];         // row stride 40 shorts = 80 B (16B-mult)
    unsigned short Al[64][40];
    unsigned short Bh[64][40];
    unsigned short Bl[64][40];
};

// ---- MFMA NT GEMM: C[i0:+64, j0:+64] = A[64x512] @ Bt[64x512].T (+ bias) ----
// 256 thr / 4 waves. Wave w: rows 16w..16w+15 x all 64 cols (4 col-tiles).
// Frag layouts (m89/m91-verified): A[m=lane&15][k=quad*8+j],
// B[n=lane&15][k=quad*8+j], D: col=lane&15, row=quad*4+reg.
template<bool BIAS>
__device__ __forceinline__
void mfma_gemm(const float* __restrict__ A, const float* __restrict__ Bt,
               float* __restrict__ C, const float* __restrict__ bias,
               float bscale, int i0, int j0, MfmaSmem& sm) {
    const int t = threadIdx.x;
    const int sr = t >> 2, sk = (t & 3) << 3;      // staging: row, k-offset
    const int lane = t & 63, w = t >> 6;
    const int fm = lane & 15, fq = (lane >> 4) << 3;

    f32x4 acc[4] = {};

    for (int k0 = 0; k0 < HD; k0 += 32) {
        __syncthreads();
        {   // stage A: 8 floats -> (Ah,Al) bf16x8
            const float* ap = &A[(size_t)(i0 + sr) * HD + k0 + sk];
            float4 a0 = *(const float4*)ap, a1 = *(const float4*)(ap + 4);
            float f[8] = {a0.x, a0.y, a0.z, a0.w, a1.x, a1.y, a1.z, a1.w};
            bf16x8 hv, lv;
            #pragma unroll
            for (int i = 0; i < 8; ++i) {
                unsigned u = __float_as_uint(f[i]);
                hv[i] = (short)(u >> 16);
                float hi = __uint_as_float(u & 0xFFFF0000u);
                lv[i] = (short)(__float_as_uint(f[i] - hi) >> 16);
            }
            *(bf16x8*)&sm.Ah[sr][sk] = hv;
            *(bf16x8*)&sm.Al[sr][sk] = lv;
        }
        {   // stage Bt identically
            const float* bp = &Bt[(size_t)(j0 + sr) * HD + k0 + sk];
            float4 b0 = *(const float4*)bp, b1 = *(const float4*)(bp + 4);
            float f[8] = {b0.x, b0.y, b0.z, b0.w, b1.x, b1.y, b1.z, b1.w};
            bf16x8 hv, lv;
            #pragma unroll
            for (int i = 0; i < 8; ++i) {
                unsigned u = __float_as_uint(f[i]);
                hv[i] = (short)(u >> 16);
                float hi = __uint_as_float(u & 0xFFFF0000u);
                lv[i] = (short)(__float_as_uint(f[i] - hi) >> 16);
            }
            *(bf16x8*)&sm.Bh[sr][sk] = hv;
            *(bf16x8*)&sm.Bl[sr][sk] = lv;
        }
        __syncthreads();

        bf16x8 ah = *(const bf16x8*)&sm.Ah[(w << 4) + fm][fq];
        bf16x8 al = *(const bf16x8*)&sm.Al[(w << 4) + fm][fq];
        #pragma unroll
        for (int ct = 0; ct < 4; ++ct) {
            bf16x8 bh = *(const bf16x8*)&sm.Bh[(ct << 4) + fm][fq];
            bf16x8 bl = *(const bf16x8*)&sm.Bl[(ct << 4) + fm][fq];
            acc[ct] = __builtin_amdgcn_mfma_f32_16x16x32_bf16(ah, bh, acc[ct], 0, 0, 0);
            acc[ct] = __builtin_amdgcn_mfma_f32_16x16x32_bf16(ah, bl, acc[ct], 0, 0, 0);
            acc[ct] = __builtin_amdgcn_mfma_f32_16x16x32_bf16(al, bh, acc[ct], 0, 0, 0);
        }
    }

    const int orow = i0 + (w << 4) + ((lane >> 4) << 2);
    #pragma unroll
    for (int ct = 0; ct < 4; ++ct) {
        const int col = j0 + (ct << 4) + fm;
        float bv = BIAS ? bscale * bias[col] : 0.f;
        #pragma unroll
        for (int r = 0; r < 4; ++r)
            C[(size_t)(orow + r) * HD + col] = acc[ct][r] + bv;
    }
}

// ---- D1: [0,1024) pool | [1024,1088) WsumT | [1088,1216) c0 ----
union D1Smem {
    float  tp[64][68];   // 17408 B transpose scratch (stride 68: 16B-aligned rows)
    float4 red[128];     // pool reduce
};

__global__ __launch_bounds__(256) void kD1(
        const float* __restrict__ x, const float* __restrict__ Wz,
        const float* __restrict__ bz, const float* __restrict__ Wzf,
        const float* __restrict__ bzf,
        float* __restrict__ P3, float* __restrict__ WsumT, float* __restrict__ c0) {
    __shared__ D1Smem sm;
    const int b = blockIdx.x, t = threadIdx.x;
    if (b < 1024) {
        // pool: block = tree; thread: col4 = t&127, half = t>>7 (32 rows each)
        const int c = t & 127, h = t >> 7;
        const float4* xp = (const float4*)x + (size_t)b * 8192 + h * 4096 + c;
        float4 acc = make_float4(0.f, 0.f, 0.f, 0.f);
        for (int r = 0; r < 32; r += 4) {
            float4 v0 = xp[(r + 0) * 128], v1 = xp[(r + 1) * 128];
            float4 v2 = xp[(r + 2) * 128], v3 = xp[(r + 3) * 128];
            acc.x += (v0.x + v1.x) + (v2.x + v3.x);
            acc.y += (v0.y + v1.y) + (v2.y + v3.y);
            acc.z += (v0.z + v1.z) + (v2.z + v3.z);
            acc.w += (v0.w + v1.w) + (v2.w + v3.w);
        }
        if (h) sm.red[c] = acc;
        __syncthreads();
        if (!h) {
            float4 o = sm.red[c];
            acc.x += o.x; acc.y += o.y; acc.z += o.z; acc.w += o.w;
            ((float4*)P3)[b * 128 + c] = acc;
        }
    } else if (b < 1088) {
        // WsumT tile: WsumT[h][j] = sum_q Wz[q][j][h]
        const int bb = b - 1024;
        const int j0t = (bb >> 3) << 6, h0t = (bb & 7) << 6;
        const int rr = t >> 4, cc = (t & 15) << 2;
        #pragma unroll
        for (int p = 0; p < 4; ++p) {
            const float* wp = &Wz[(size_t)(j0t + rr + 16 * p) * HD + h0t + cc];
            float4 s = *(const float4*)wp;
            #pragma unroll
            for (int q = 1; q < 4; ++q) {
                float4 v = *(const float4*)(wp + q * 262144);
                s.x += v.x; s.y += v.y; s.z += v.z; s.w += v.w;
            }
            *(float4*)&sm.tp[rr + 16 * p][cc] = s;   // tp[j][h]
        }
        __syncthreads();
        #pragma unroll
        for (int p = 0; p < 4; ++p) {
            const int hr = rr + 16 * p;
            float4 o = make_float4(sm.tp[cc + 0][hr], sm.tp[cc + 1][hr],
                                   sm.tp[cc + 2][hr], sm.tp[cc + 3][hr]);
            *(float4*)&WsumT[(size_t)(h0t + hr) * HD + j0t + cc] = o;
        }
    } else {
        // c0[j] = 4*(dot(bsum, Wzf[j,:]) + bzf[j]); one j per wave
        const int lane = t & 63, w = t >> 6, hb = lane << 3;
        const int j = (b - 1088) * 4 + w;
        float4 s0 = *(const float4*)&bz[hb];
        float4 s1 = *(const float4*)&bz[hb + 4];
        #pragma unroll
        for (int q = 1; q < 4; ++q) {
            float4 t0 = *(const float4*)&bz[q * HD + hb];
            float4 t1 = *(const float4*)&bz[q * HD + hb + 4];
            s0.x += t0.x; s0.y += t0.y; s0.z += t0.z; s0.w += t0.w;
            s1.x += t1.x; s1.y += t1.y; s1.z += t1.z; s1.w += t1.w;
        }
        const float4* wr = (const float4*)&Wzf[(size_t)j * HD + hb];
        float4 w0 = wr[0], w1 = wr[1];
        float p = w0.x * s0.x + w0.y * s0.y + w0.z * s0.z + w0.w * s0.w
                + w1.x * s1.x + w1.y * s1.y + w1.z * s1.z + w1.w * s1.w;
        #pragma unroll
        for (int off = 32; off > 0; off >>= 1) p += __shfl_down(p, off);
        if (lane == 0) c0[j] = 4.f * (p + bzf[j]);
    }
}

// ---- D2: [0,64) M = NT(Wzf,WsumT) | [64,128) MT = NT(WsumT,Wzf) ----
__global__ __launch_bounds__(256) void kD2(
        const float* __restrict__ Wzf, const float* __restrict__ WsumT,
        float* __restrict__ M, float* __restrict__ MT) {
    __shared__ MfmaSmem sm;
    const int b = blockIdx.x;
    if (b < 64) {
        mfma_gemm<false>(Wzf, WsumT, M, nullptr, 0.f,
                         (b >> 3) << 6, (b & 7) << 6, sm);
    } else {
        const int bb = b - 64;
        mfma_gemm<false>(WsumT, Wzf, MT, nullptr, 0.f,
                         (bb >> 3) << 6, (bb & 7) << 6, sm);
    }
}

// ---- D3: [0,128) Y1 = NT(P3,M)+16c | [128,192) M2 = NT(M,MT) | [192,320) u ----
__global__ __launch_bounds__(256) void kD3(
        const float* __restrict__ P3, const float* __restrict__ M,
        const float* __restrict__ MT, const float* __restrict__ c0,
        float* __restrict__ Y1, float* __restrict__ M2, float* __restrict__ u) {
    __shared__ MfmaSmem sm;
    const int b = blockIdx.x, t = threadIdx.x;
    if (b < 128) {
        mfma_gemm<true>(P3, M, Y1, c0, 16.f, (b >> 3) << 6, (b & 7) << 6, sm);
    } else if (b < 192) {
        const int bb = b - 128;
        mfma_gemm<false>(M, MT, M2, nullptr, 0.f,
                         (bb >> 3) << 6, (bb & 7) << 6, sm);
    } else {
        // u[j] = 4*dot(M[j,:], c0) + c0[j]; one j per wave
        const int lane = t & 63, w = t >> 6, hb = lane << 3;
        const int j = (b - 192) * 4 + w;
        const float4* mr = (const float4*)&M[(size_t)j * HD + hb];
        const float4* cr = (const float4*)&c0[hb];
        float4 m0 = mr[0], m1 = mr[1], q0 = cr[0], q1 = cr[1];
        float p = m0.x * q0.x + m0.y * q0.y + m0.z * q0.z + m0.w * q0.w
                + m1.x * q1.x + m1.y * q1.y + m1.z * q1.z + m1.w * q1.w;
        #pragma unroll
        for (int off = 32; off > 0; off >>= 1) p += __shfl_down(p, off);
        if (lane == 0) u[j] = 4.f * p + c0[j];
    }
}

// ---- D4: out = NT(Y1, M2) + u ----
__global__ __launch_bounds__(256) void kD4(
        const float* __restrict__ Y1, const float* __restrict__ M2,
        const float* __restrict__ u, float* __restrict__ out) {
    __shared__ MfmaSmem sm;
    const int b = blockIdx.x;
    mfma_gemm<true>(Y1, M2, out, u, 1.f, (b >> 3) << 6, (b & 7) << 6, sm);
}

extern "C" void kernel_launch(void* const* d_in, const int* in_sizes, int n_in,
                              void* d_out, int out_size, void* d_ws, size_t ws_size,
                              hipStream_t stream) {
    const float* x   = (const float*)d_in[0];
    const float* Wz  = (const float*)d_in[1];
    const float* bz  = (const float*)d_in[2];
    const float* Wzf = (const float*)d_in[3];
    const float* bzf = (const float*)d_in[4];
    float* out = (float*)d_out;

    float* ws    = (float*)d_ws;
    float* P3    = ws;                 // 1024*512
    float* Y1    = ws + 524288;        // 1024*512
    float* WsumT = ws + 1048576;       // 512*512
    float* M     = ws + 1310720;       // 512*512
    float* MT    = ws + 1572864;       // 512*512
    float* M2    = ws + 1835008;       // 512*512
    float* c0    = ws + 2097152;       // 512
    float* u     = ws + 2097664;       // 512

    hipLaunchKernelGGL(kD1, dim3(1216), dim3(256), 0, stream,
                       x, Wz, bz, Wzf, bzf, P3, WsumT, c0);
    hipLaunchKernelGGL(kD2, dim3(128), dim3(256), 0, stream, Wzf, WsumT, M, MT);
    hipLaunchKernelGGL(kD3, dim3(320), dim3(256), 0, stream,
                       P3, M, MT, c0, Y1, M2, u);
    hipLaunchKernelGGL(kD4, dim3(128), dim3(256), 0, stream, Y1, M2, u, out);
}

// Round 9
// 254.061 us; speedup vs baseline: 1.5031x; 1.0388x over previous
//
#include <hip/hip_runtime.h>

// Collapse: out = ((P3@M.T + 16c)@M.T + 4c)@M.T + c,  M = Wzf@Wsum.
// NT-form chain: WsumT = sum_q Wz[q].T ; M = NT(Wzf,WsumT) ; MT = NT(WsumT,Wzf)
//   M2 = NT(M,MT) = M@M ; Y1 = NT(P3,M)+16c ; u = 4c@M.T+c ; out = NT(Y1,M2)+u
// MFMA 16x16x32 bf16, exact 2-term split: A*B ~= Ah*Bh + Ah*Bl + Al*Bh.
// Pool: 2-stage, 2048 partial-blocks (32 waves/CU) + reduce folded into D2.
// D1{poolA,WsumT,c0}(2240) -> D2{M,MT,reduce}(384) -> D3{Y1,M2,u}(320) -> D4{out}(128)

#define HD 512

typedef __attribute__((ext_vector_type(8))) short bf16x8;
typedef __attribute__((ext_vector_type(4))) float f32x4;

struct __align__(16) MfmaSmem {        // 20480 B
    unsigned short Ah[64][40];         // row stride 40 shorts = 80 B
    unsigned short Al[64][40];
    unsigned short Bh[64][40];
    unsigned short Bl[64][40];
};

__device__ __forceinline__ void split8(const float4& v0, const float4& v1,
                                       bf16x8& hv, bf16x8& lv) {
    float f[8] = {v0.x, v0.y, v0.z, v0.w, v1.x, v1.y, v1.z, v1.w};
    #pragma unroll
    for (int i = 0; i < 8; ++i) {
        unsigned u = __float_as_uint(f[i]);
        hv[i] = (short)(u >> 16);
        float hi = __uint_as_float(u & 0xFFFF0000u);
        lv[i] = (short)(__float_as_uint(f[i] - hi) >> 16);
    }
}

// ---- MFMA NT GEMM: C[i0:+64, j0:+64] = A[64x512] @ Bt[64x512].T (+ bias) ----
// 256 thr / 4 waves; wave w: rows 16w..16w+15 x 4 col-tiles. Software-pipelined:
// next k-tile's global loads issue before the MFMA phase consumes current LDS.
template<bool BIAS>
__device__ __forceinline__
void mfma_gemm(const float* __restrict__ A, const float* __restrict__ Bt,
               float* __restrict__ C, const float* __restrict__ bias,
               float bscale, int i0, int j0, MfmaSmem& sm) {
    const int t = threadIdx.x;
    const int sr = t >> 2, sk = (t & 3) << 3;      // staging: row, k-offset
    const int lane = t & 63, w = t >> 6;
    const int fm = lane & 15, fq = (lane >> 4) << 3;

    const float* ap = &A[(size_t)(i0 + sr) * HD + sk];
    const float* bp = &Bt[(size_t)(j0 + sr) * HD + sk];
    float4 a0 = *(const float4*)ap,      a1 = *(const float4*)(ap + 4);
    float4 b0 = *(const float4*)bp,      b1 = *(const float4*)(bp + 4);

    f32x4 acc[4] = {};

    for (int it = 0; it < 16; ++it) {
        __syncthreads();                 // prior MFMA reads of LDS done
        bf16x8 hv, lv;
        split8(a0, a1, hv, lv);
        *(bf16x8*)&sm.Ah[sr][sk] = hv;
        *(bf16x8*)&sm.Al[sr][sk] = lv;
        split8(b0, b1, hv, lv);
        *(bf16x8*)&sm.Bh[sr][sk] = hv;
        *(bf16x8*)&sm.Bl[sr][sk] = lv;
        __syncthreads();

        if (it < 15) {                   // prefetch next tile (hidden by MFMA)
            const int k0n = (it + 1) << 5;
            a0 = *(const float4*)(ap + k0n);
            a1 = *(const float4*)(ap + k0n + 4);
            b0 = *(const float4*)(bp + k0n);
            b1 = *(const float4*)(bp + k0n + 4);
        }

        bf16x8 ah = *(const bf16x8*)&sm.Ah[(w << 4) + fm][fq];
        bf16x8 al = *(const bf16x8*)&sm.Al[(w << 4) + fm][fq];
        #pragma unroll
        for (int ct = 0; ct < 4; ++ct) {
            bf16x8 bh = *(const bf16x8*)&sm.Bh[(ct << 4) + fm][fq];
            bf16x8 bl = *(const bf16x8*)&sm.Bl[(ct << 4) + fm][fq];
            acc[ct] = __builtin_amdgcn_mfma_f32_16x16x32_bf16(ah, bh, acc[ct], 0, 0, 0);
            acc[ct] = __builtin_amdgcn_mfma_f32_16x16x32_bf16(ah, bl, acc[ct], 0, 0, 0);
            acc[ct] = __builtin_amdgcn_mfma_f32_16x16x32_bf16(al, bh, acc[ct], 0, 0, 0);
        }
    }

    const int orow = i0 + (w << 4) + ((lane >> 4) << 2);
    #pragma unroll
    for (int ct = 0; ct < 4; ++ct) {
        const int col = j0 + (ct << 4) + fm;
        float bv = BIAS ? bscale * bias[col] : 0.f;
        #pragma unroll
        for (int r = 0; r < 4; ++r)
            C[(size_t)(orow + r) * HD + col] = acc[ct][r] + bv;
    }
}

// ---- D1: [0,2048) pool partials | [2048,2112) WsumT | [2112,2240) c0 ----
union D1Smem {
    float  tp[64][68];   // transpose scratch
    float4 red[128];     // pool reduce
};

__global__ __launch_bounds__(256) void kD1(
        const float* __restrict__ x, const float* __restrict__ Wz,
        const float* __restrict__ bz, const float* __restrict__ Wzf,
        const float* __restrict__ bzf,
        float* __restrict__ part, float* __restrict__ WsumT, float* __restrict__ c0) {
    __shared__ D1Smem sm;
    const int b = blockIdx.x, t = threadIdx.x;
    if (b < 2048) {
        // block = (tree, row-half); thread: col4 = t&127, sub-half = t>>7
        const int tree = b >> 1, half = b & 1;
        const int c = t & 127, sub = t >> 7;
        const float4* xp = (const float4*)x + (size_t)tree * 8192
                         + (half * 32 + sub * 16) * 128 + c;
        float4 acc = make_float4(0.f, 0.f, 0.f, 0.f);
        #pragma unroll
        for (int g = 0; g < 2; ++g) {
            float4 v[8];
            #pragma unroll
            for (int i = 0; i < 8; ++i) v[i] = xp[(size_t)(g * 8 + i) * 128];
            #pragma unroll
            for (int i = 0; i < 8; ++i) {
                acc.x += v[i].x; acc.y += v[i].y; acc.z += v[i].z; acc.w += v[i].w;
            }
        }
        if (sub) sm.red[c] = acc;
        __syncthreads();
        if (!sub) {
            float4 o = sm.red[c];
            acc.x += o.x; acc.y += o.y; acc.z += o.z; acc.w += o.w;
            ((float4*)part)[b * 128 + c] = acc;
        }
    } else if (b < 2112) {
        // WsumT[h][j] = sum_q Wz[q][j][h], one 64x64 tile per block
        const int bb = b - 2048;
        const int j0t = (bb >> 3) << 6, h0t = (bb & 7) << 6;
        const int rr = t >> 4, cc = (t & 15) << 2;
        #pragma unroll
        for (int p = 0; p < 4; ++p) {
            const float* wp = &Wz[(size_t)(j0t + rr + 16 * p) * HD + h0t + cc];
            float4 s = *(const float4*)wp;
            #pragma unroll
            for (int q = 1; q < 4; ++q) {
                float4 v = *(const float4*)(wp + q * 262144);
                s.x += v.x; s.y += v.y; s.z += v.z; s.w += v.w;
            }
            *(float4*)&sm.tp[rr + 16 * p][cc] = s;
        }
        __syncthreads();
        #pragma unroll
        for (int p = 0; p < 4; ++p) {
            const int hr = rr + 16 * p;
            float4 o = make_float4(sm.tp[cc + 0][hr], sm.tp[cc + 1][hr],
                                   sm.tp[cc + 2][hr], sm.tp[cc + 3][hr]);
            *(float4*)&WsumT[(size_t)(h0t + hr) * HD + j0t + cc] = o;
        }
    } else {
        // c0[j] = 4*(dot(bsum, Wzf[j,:]) + bzf[j]); one j per wave
        const int lane = t & 63, w = t >> 6, hb = lane << 3;
        const int j = (b - 2112) * 4 + w;
        float4 s0 = *(const float4*)&bz[hb];
        float4 s1 = *(const float4*)&bz[hb + 4];
        #pragma unroll
        for (int q = 1; q < 4; ++q) {
            float4 t0 = *(const float4*)&bz[q * HD + hb];
            float4 t1 = *(const float4*)&bz[q * HD + hb + 4];
            s0.x += t0.x; s0.y += t0.y; s0.z += t0.z; s0.w += t0.w;
            s1.x += t1.x; s1.y += t1.y; s1.z += t1.z; s1.w += t1.w;
        }
        const float4* wr = (const float4*)&Wzf[(size_t)j * HD + hb];
        float4 w0 = wr[0], w1 = wr[1];
        float p = w0.x * s0.x + w0.y * s0.y + w0.z * s0.z + w0.w * s0.w
                + w1.x * s1.x + w1.y * s1.y + w1.z * s1.z + w1.w * s1.w;
        #pragma unroll
        for (int off = 32; off > 0; off >>= 1) p += __shfl_down(p, off);
        if (lane == 0) c0[j] = 4.f * (p + bzf[j]);
    }
}

// ---- D2: [0,64) M | [64,128) MT | [128,384) reduce partials -> P3 ----
__global__ __launch_bounds__(256) void kD2(
        const float* __restrict__ Wzf, const float* __restrict__ WsumT,
        const float* __restrict__ part,
        float* __restrict__ M, float* __restrict__ MT, float* __restrict__ P3) {
    __shared__ MfmaSmem sm;
    const int b = blockIdx.x, t = threadIdx.x;
    if (b < 64) {
        mfma_gemm<false>(Wzf, WsumT, M, nullptr, 0.f,
                         (b >> 3) << 6, (b & 7) << 6, sm);
    } else if (b < 128) {
        const int bb = b - 64;
        mfma_gemm<false>(WsumT, Wzf, MT, nullptr, 0.f,
                         (bb >> 3) << 6, (bb & 7) << 6, sm);
    } else {
        const int gid = (b - 128) * 256 + t;       // [0, 65536)
        const float4* p4 = (const float4*)part;
        float4* o4 = (float4*)P3;
        #pragma unroll
        for (int h = 0; h < 2; ++h) {
            const int i = gid + h * 65536;         // P3 float4 index
            const int tree = i >> 7, c = i & 127;
            float4 pa = p4[(size_t)(2 * tree) * 128 + c];
            float4 pb = p4[(size_t)(2 * tree + 1) * 128 + c];
            pa.x += pb.x; pa.y += pb.y; pa.z += pb.z; pa.w += pb.w;
            o4[i] = pa;
        }
    }
}

// ---- D3: [0,128) Y1 = NT(P3,M)+16c | [128,192) M2 = NT(M,MT) | [192,320) u ----
__global__ __launch_bounds__(256) void kD3(
        const float* __restrict__ P3, const float* __restrict__ M,
        const float* __restrict__ MT, const float* __restrict__ c0,
        float* __restrict__ Y1, float* __restrict__ M2, float* __restrict__ u) {
    __shared__ MfmaSmem sm;
    const int b = blockIdx.x, t = threadIdx.x;
    if (b < 128) {
        mfma_gemm<true>(P3, M, Y1, c0, 16.f, (b >> 3) << 6, (b & 7) << 6, sm);
    } else if (b < 192) {
        const int bb = b - 128;
        mfma_gemm<false>(M, MT, M2, nullptr, 0.f,
                         (bb >> 3) << 6, (bb & 7) << 6, sm);
    } else {
        const int lane = t & 63, w = t >> 6, hb = lane << 3;
        const int j = (b - 192) * 4 + w;
        const float4* mr = (const float4*)&M[(size_t)j * HD + hb];
        const float4* cr = (const float4*)&c0[hb];
        float4 m0 = mr[0], m1 = mr[1], q0 = cr[0], q1 = cr[1];
        float p = m0.x * q0.x + m0.y * q0.y + m0.z * q0.z + m0.w * q0.w
                + m1.x * q1.x + m1.y * q1.y + m1.z * q1.z + m1.w * q1.w;
        #pragma unroll
        for (int off = 32; off > 0; off >>= 1) p += __shfl_down(p, off);
        if (lane == 0) u[j] = 4.f * p + c0[j];
    }
}

// ---- D4: out = NT(Y1, M2) + u ----
__global__ __launch_bounds__(256) void kD4(
        const float* __restrict__ Y1, const float* __restrict__ M2,
        const float* __restrict__ u, float* __restrict__ out) {
    __shared__ MfmaSmem sm;
    const int b = blockIdx.x;
    mfma_gemm<true>(Y1, M2, out, u, 1.f, (b >> 3) << 6, (b & 7) << 6, sm);
}

extern "C" void kernel_launch(void* const* d_in, const int* in_sizes, int n_in,
                              void* d_out, int out_size, void* d_ws, size_t ws_size,
                              hipStream_t stream) {
    const float* x   = (const float*)d_in[0];
    const float* Wz  = (const float*)d_in[1];
    const float* bz  = (const float*)d_in[2];
    const float* Wzf = (const float*)d_in[3];
    const float* bzf = (const float*)d_in[4];
    float* out = (float*)d_out;

    float* ws    = (float*)d_ws;
    float* P3    = ws;                 // 1024*512
    float* Y1    = ws + 524288;        // 1024*512
    float* WsumT = ws + 1048576;       // 512*512
    float* M     = ws + 1310720;       // 512*512
    float* MT    = ws + 1572864;       // 512*512
    float* M2    = ws + 1835008;       // 512*512
    float* part  = ws + 2097152;       // 2048*512 partials (4 MB)
    float* c0    = ws + 3145728;       // 512
    float* u     = ws + 3146240;       // 512

    hipLaunchKernelGGL(kD1, dim3(2240), dim3(256), 0, stream,
                       x, Wz, bz, Wzf, bzf, part, WsumT, c0);
    hipLaunchKernelGGL(kD2, dim3(384), dim3(256), 0, stream,
                       Wzf, WsumT, part, M, MT, P3);
    hipLaunchKernelGGL(kD3, dim3(320), dim3(256), 0, stream,
                       P3, M, MT, c0, Y1, M2, u);
    hipLaunchKernelGGL(kD4, dim3(128), dim3(256), 0, stream, Y1, M2, u, out);
}